// Round 6
// baseline (178.189 us; speedup 1.0000x reference)
//
#include <hip/hip_runtime.h>
#include <hip/hip_bf16.h>

typedef __bf16 bf16_t;
typedef __bf16 bf16x8 __attribute__((ext_vector_type(8)));
typedef float  f32x4  __attribute__((ext_vector_type(4)));

constexpr int S  = 2048;
constexpr int H  = 32;
constexpr int D  = 128;
constexpr int BR = 128;   // q rows per tile (16 per wave, 8 waves)
constexpr int SC = 32;    // kv positions per chunk
constexpr int NT = S / BR;        // 16 q-tiles
constexpr int KSTR  = 136;        // Klds row stride (elems)
constexpr int VSTR2 = 20;         // Vt2 row stride (dwords)

// workspace layout (f32 indices): O_B partials, then l_A, then l_B
constexpr size_t WS_OB  = 0;                              // [pr][h][128r][128d]
constexpr size_t WS_LA  = (size_t)8 * 32 * 128 * 128;     // [pr][h][128r]
constexpr size_t WS_LB  = WS_LA + (size_t)8 * 32 * 128;
constexpr size_t WS_F32 = WS_LB + (size_t)8 * 32 * 128;   // 4,202,496 f32

__device__ __forceinline__ bf16x8 cvt8(f32x4 lo, f32x4 hi) {
    bf16x8 r;
#pragma unroll
    for (int j = 0; j < 4; ++j) { r[j] = (bf16_t)lo[j]; r[4 + j] = (bf16_t)hi[j]; }
    return r;
}
__device__ __forceinline__ uint32_t pk2(float a, float b) {
    union { uint32_t u; bf16_t h[2]; } r;
    r.h[0] = (bf16_t)a; r.h[1] = (bf16_t)b;   // kv even -> low, kv odd -> high
    return r.u;
}

// Flash attention fwd, f32 I/O, bf16 MFMA, S^T orientation, 16 q rows/wave.
//
// EQUAL-WORK grid, round-2-proven block shape (512 thr, 8 waves, 37.9 KB LDS):
// pair (pr, 15-pr) has 68 kv-chunks total; split into TWO blocks of exactly
// 34 chunks: block A = tile pr (4pr+4 chunks) + first 30-4pr chunks of tile
// 15-pr (two sequential phases); block B = last 34 chunks of tile 15-pr.
// 512 equal blocks, 2/CU -> 16 waves/CU steady, zero tail (rounds 0/2
// measured 14%/28% occupancy exactly matching the work/makespan model of the
// old unbalanced grids). Fixed-max softmax is LINEAR in kv -> partials merge
// by addition: A writes its big-tile O partial UNNORMALIZED to out + l_A to
// ws; B writes O_B + l_B to ws; fa_merge does out = (out+O_B)/(l_A+l_B).
// A's prefix chunks are provably fully unmasked (max kv0 = 928 < min q row
// 1039 of any split tile), so A phase 1 takes the no-mask fast path.
//
// P never touches LDS: K rows staged under permutation
//   pi^-1(kv) = (kv&4) ? 16 + 4*(kv>>3) + (kv&3) : 4*(kv>>3) + (kv&3)
// so the S^T C-fragment holds exactly the kv = quad*8 + j values the PV
// B-fragment needs, in register order {frag0[0..3], frag1[0..3]}.
__global__ __launch_bounds__(512)
__attribute__((amdgpu_waves_per_eu(4, 4)))
void fa_bal(const float* __restrict__ q, const float* __restrict__ kvp,
            float* __restrict__ out, float* __restrict__ ws) {
    __shared__ __align__(16) bf16_t   Klds[2][SC * KSTR];  // 2 x 8704 B
    __shared__ __align__(16) uint32_t Vt2[2][D * VSTR2];   // 2 x 10240 B

    const int bx   = blockIdx.x;
    const int h    = bx & 31;               // heads innermost
    const int u    = bx >> 5;               // 0..15
    const int pr   = u >> 1;                // 0..7 tile pair (pr, 15-pr)
    const int role = u & 1;                 // 0 = A, 1 = B

    const int t    = threadIdx.x;           // 0..511
    const int w    = t >> 6;                // 0..7
    const int lane = t & 63;
    const int quad = lane >> 4;
    const int m    = lane & 15;

    const float sc = 0.08838834764831845f * 1.44269504088896340f; // scale*log2e

    // K staging: thread stages row rk (permuted), d-chunk kc*8..+7
    const int rk  = t >> 4;                 // 0..31
    const int kc  = t & 15;
    const int lrk = ((rk >> 3) << 2) + (rk & 3) + ((rk & 4) ? 16 : 0); // pi^-1
    // V staging: thread stages kv pair (2vp,2vp+1), dims d0v..d0v+3
    const int vp  = t >> 5;                 // 0..15
    const int dh  = t & 31;                 // 0..31
    const int d0v = dh * 4;
    const int vpos = vp ^ (((dh >> 1) & 3) << 2);   // column swizzle

    const size_t rowstep = (size_t)2 * H * D;      // f32 elems per kv row
    const size_t cstep   = (size_t)SC * rowstep;   // one 32-kv chunk

    const float* pk;
    const float* pv0;
    f32x4 kr[2], vr0, vr1;
    auto ldregs = [&]() {
        kr[0] = *(const f32x4*)pk;
        kr[1] = *(const f32x4*)(pk + 4);
        vr0   = *(const f32x4*)pv0;             // kv row 2*vp
        vr1   = *(const f32x4*)(pv0 + rowstep); // kv row 2*vp+1
    };
    auto stage = [&](int b) {
        *(bf16x8*)&Klds[b][lrk * KSTR + kc * 8] = cvt8(kr[0], kr[1]);
#pragma unroll
        for (int jq = 0; jq < 4; ++jq)
            Vt2[b][(d0v + jq) * VSTR2 + vpos] = pk2(vr0[jq], vr1[jq]);
    };

    const int nph = (role == 0) ? 2 : 1;
    for (int ph = 0; ph < nph; ++ph) {
        // phase schedule: chunk window [beg, end) of `tile`; mode selects epilogue
        int tile, beg, end, mode;
        if (role == 0) {
            if (ph == 0) { tile = pr;      beg = 0;           end = 4 * (pr + 1);  mode = 0; }
            else         { tile = 15 - pr; beg = 0;           end = 30 - 4 * pr;   mode = 1; }
        } else           { tile = 15 - pr; beg = 30 - 4 * pr; end = 4 * (16 - pr); mode = 2; }

        const int q0    = tile * BR;
        const int qp0   = q0 + w * 16 + m;
        const int qmaxw = q0 + w * 16 + 15;
        const int n     = end - beg;

        pk  = kvp + (((size_t)rk * 2 + 0) * H + h) * D + kc * 8 + (size_t)beg * cstep;
        pv0 = kvp + (((size_t)(2 * vp) * 2 + 1) * H + h) * D + d0v + (size_t)beg * cstep;

        // ---- Q fragments (B-operand of S^T), 4 d-chunks, pre-scaled
        bf16x8 aq[4];
#pragma unroll
        for (int c = 0; c < 4; ++c) {
            const float* p = q + ((size_t)qp0 * H + h) * D + c * 32 + quad * 8;
            f32x4 lo = *(const f32x4*)p * sc;
            f32x4 hi = *(const f32x4*)(p + 4) * sc;
            aq[c] = cvt8(lo, hi);
        }

        f32x4 o[8];
#pragma unroll
        for (int idx = 0; idx < 8; ++idx) o[idx] = (f32x4)0.f;
        float lrow = 0.f;

        // ---- pipeline head: chunk beg staged in bank 0, beg+1 in registers
        ldregs();
        stage(0);
        if (n > 1) { pk += cstep; pv0 += cstep; ldregs(); }
        __syncthreads();

        for (int it = 0; it < n; ++it) {
            const int kv0 = (beg + it) * SC;
            const int cur = it & 1;
            const bool active = (kv0 <= qmaxw);

            bf16x8 bp;
            if (active) {
                // ---- S^T = K Q^T : 2 kv-half fragments x 4 d-chunks
                f32x4 sA[2];
                sA[0] = (f32x4)0.f; sA[1] = (f32x4)0.f;
                __builtin_amdgcn_s_setprio(1);
#pragma unroll
                for (int c = 0; c < 4; ++c) {
                    bf16x8 ak0 = *(const bf16x8*)&Klds[cur][m * KSTR + c * 32 + quad * 8];
                    bf16x8 ak1 = *(const bf16x8*)&Klds[cur][(16 + m) * KSTR + c * 32 + quad * 8];
                    sA[0] = __builtin_amdgcn_mfma_f32_16x16x32_bf16(ak0, aq[c], sA[0], 0, 0, 0);
                    sA[1] = __builtin_amdgcn_mfma_f32_16x16x32_bf16(ak1, aq[c], sA[1], 0, 0, 0);
                }
                __builtin_amdgcn_s_setprio(0);

                // ---- fixed-max softmax: p = exp2(min(v,80)); frag0 <-> kv 8q+r,
                // frag1 <-> kv 8q+4+r (K-row permutation). Full tiles skip mask.
                const int limb = q0 + w * 16 - kv0;   // wave-uniform
                float p[8], rs = 0.f;
                if (limb >= 31) {
#pragma unroll
                    for (int r = 0; r < 4; ++r) {
                        p[r]     = __builtin_amdgcn_exp2f(fminf(sA[0][r], 80.f));
                        p[4 + r] = __builtin_amdgcn_exp2f(fminf(sA[1][r], 80.f));
                        rs += p[r] + p[4 + r];
                    }
                } else {
                    const int lim = limb + m;
#pragma unroll
                    for (int r = 0; r < 4; ++r) {
                        float e0 = __builtin_amdgcn_exp2f(fminf(sA[0][r], 80.f));
                        float e1 = __builtin_amdgcn_exp2f(fminf(sA[1][r], 80.f));
                        p[r]     = (quad * 8 + r     <= lim) ? e0 : 0.f;
                        p[4 + r] = (quad * 8 + 4 + r <= lim) ? e1 : 0.f;
                        rs += p[r] + p[4 + r];
                    }
                }
                lrow += rs;
#pragma unroll
                for (int r = 0; r < 4; ++r) { bp[r] = (bf16_t)p[r]; bp[4 + r] = (bf16_t)p[4 + r]; }
            }

            // ---- stage chunk it+1 into other bank; prefetch it+2 (all waves)
            if (it + 1 < n) {
                stage(cur ^ 1);
                if (it + 2 < n) { pk += cstep; pv0 += cstep; ldregs(); }
            }

            if (active) {
                // ---- O^T += V^T P^T
                __builtin_amdgcn_s_setprio(1);
#pragma unroll
                for (int tt = 0; tt < 8; ++tt) {
                    const int dd  = tt * 16 + m;
                    const int grp = quad ^ ((dd >> 3) & 3);
                    bf16x8 av = *(const bf16x8*)&Vt2[cur][dd * VSTR2 + grp * 4];
                    o[tt] = __builtin_amdgcn_mfma_f32_16x16x32_bf16(av, bp, o[tt], 0, 0, 0);
                }
                __builtin_amdgcn_s_setprio(0);
            }
            __syncthreads();
        }

        // ---- cross-lane lrow reduction (deferred; sum is linear in kv)
        lrow += __shfl_xor(lrow, 16);
        lrow += __shfl_xor(lrow, 32);

        // ---- epilogue by mode. O^T layout: col=q=m, row=d=quad*4+r
        if (mode == 0) {            // sole owner: normalize, final store
            const float inv = 1.0f / lrow;
            float* op = out + ((size_t)qp0 * H + h) * D;
#pragma unroll
            for (int tt = 0; tt < 8; ++tt) {
                f32x4 val = o[tt] * inv;
                *(f32x4*)(op + tt * 16 + quad * 4) = val;
            }
        } else if (mode == 1) {     // A: unnormalized partial -> out, l_A -> ws
            float* op = out + ((size_t)qp0 * H + h) * D;
#pragma unroll
            for (int tt = 0; tt < 8; ++tt)
                *(f32x4*)(op + tt * 16 + quad * 4) = o[tt];
            if (quad == 0)
                ws[WS_LA + ((size_t)pr * 32 + h) * 128 + w * 16 + m] = lrow;
        } else {                    // B: partial -> ws, l_B -> ws
            float* wp = ws + WS_OB + ((size_t)pr * 32 + h) * 16384
                           + (size_t)(w * 16 + m) * 128;
#pragma unroll
            for (int tt = 0; tt < 8; ++tt)
                *(f32x4*)(wp + tt * 16 + quad * 4) = o[tt];
            if (quad == 0)
                ws[WS_LB + ((size_t)pr * 32 + h) * 128 + w * 16 + m] = lrow;
        }
        // next phase's stage(0) only touches LDS; the loop-final barrier above
        // already ordered all LDS reads before it. Global epilogue needs no sync.
    }
}

// merge split tiles: out = (out_A + O_B) / (l_A + l_B)
__global__ __launch_bounds__(256)
void fa_merge(float* __restrict__ out, const float* __restrict__ ws) {
    const int mb = blockIdx.x;          // 0..255
    const int pr = mb >> 5, h = mb & 31;
    const int q0 = (15 - pr) * BR;
    const int tid = threadIdx.x;
    const int d4 = tid & 31;            // d = d4*4
    const int rg = tid >> 5;            // 0..7
    const float* lA = ws + WS_LA + ((size_t)pr * 32 + h) * 128;
    const float* lB = ws + WS_LB + ((size_t)pr * 32 + h) * 128;
    const float* OB = ws + WS_OB + ((size_t)pr * 32 + h) * 16384;
#pragma unroll
    for (int k = 0; k < 16; ++k) {
        const int r = rg * 16 + k;
        const float inv = 1.0f / (lA[r] + lB[r]);
        const size_t oidx = ((size_t)(q0 + r) * H + h) * D + d4 * 4;
        f32x4 a = *(const f32x4*)(out + oidx);
        f32x4 b = *(const f32x4*)(OB + (size_t)r * 128 + d4 * 4);
        *(f32x4*)(out + oidx) = (a + b) * inv;
    }
}

// fallback: round-2 kernel verbatim (used when ws is too small)
__global__ __launch_bounds__(512)
__attribute__((amdgpu_waves_per_eu(4, 4)))
void fa_fwd_r2(const float* __restrict__ q, const float* __restrict__ kvp,
               float* __restrict__ out) {
    __shared__ __align__(16) bf16_t   Klds[2][SC * KSTR];
    __shared__ __align__(16) uint32_t Vt2[2][D * VSTR2];

    const int bx = blockIdx.x;
    const int h  = bx & 31;
    const int i  = bx >> 5;
    const int qtile = (i < 8) ? (15 - i) : (i - 8);
    const int q0    = qtile * BR;

    const int t    = threadIdx.x;
    const int w    = t >> 6;
    const int lane = t & 63;
    const int quad = lane >> 4;
    const int m    = lane & 15;

    const float sc = 0.08838834764831845f * 1.44269504088896340f;

    const int rk  = t >> 4;
    const int kc  = t & 15;
    const int lrk = ((rk >> 3) << 2) + (rk & 3) + ((rk & 4) ? 16 : 0);
    const int vp  = t >> 5;
    const int dh  = t & 31;
    const int d0v = dh * 4;
    const int vpos = vp ^ (((dh >> 1) & 3) << 2);

    const size_t rowstep = (size_t)2 * H * D;
    const size_t tstep   = (size_t)SC * rowstep;
    const float* pk  = kvp + (((size_t)rk * 2 + 0) * H + h) * D + kc * 8;
    const float* pv0 = kvp + (((size_t)(2 * vp) * 2 + 1) * H + h) * D + d0v;

    const int qp0   = q0 + w * 16 + m;
    const int nkv   = (qtile + 1) * (BR / SC);
    const int qmaxw = q0 + w * 16 + 15;

    bf16x8 aq[4];
#pragma unroll
    for (int c = 0; c < 4; ++c) {
        const float* p = q + ((size_t)qp0 * H + h) * D + c * 32 + quad * 8;
        f32x4 lo = *(const f32x4*)p * sc;
        f32x4 hi = *(const f32x4*)(p + 4) * sc;
        aq[c] = cvt8(lo, hi);
    }

    f32x4 o[8];
#pragma unroll
    for (int idx = 0; idx < 8; ++idx) o[idx] = (f32x4)0.f;
    float lrow = 0.f;

    f32x4 kr[2], vr0, vr1;
    auto ldregs = [&]() {
        kr[0] = *(const f32x4*)pk;
        kr[1] = *(const f32x4*)(pk + 4);
        vr0   = *(const f32x4*)pv0;
        vr1   = *(const f32x4*)(pv0 + rowstep);
    };
    auto stage = [&](int b) {
        *(bf16x8*)&Klds[b][lrk * KSTR + kc * 8] = cvt8(kr[0], kr[1]);
#pragma unroll
        for (int jq = 0; jq < 4; ++jq)
            Vt2[b][(d0v + jq) * VSTR2 + vpos] = pk2(vr0[jq], vr1[jq]);
    };

    ldregs();
    stage(0);
    if (nkv > 1) { pk += tstep; pv0 += tstep; ldregs(); }
    __syncthreads();

    for (int kb = 0; kb < nkv; ++kb) {
        const int kv0 = kb * SC;
        const int cur = kb & 1;
        const bool active = (kv0 <= qmaxw);

        bf16x8 bp;
        if (active) {
            f32x4 sA[2];
            sA[0] = (f32x4)0.f; sA[1] = (f32x4)0.f;
            __builtin_amdgcn_s_setprio(1);
#pragma unroll
            for (int c = 0; c < 4; ++c) {
                bf16x8 ak0 = *(const bf16x8*)&Klds[cur][m * KSTR + c * 32 + quad * 8];
                bf16x8 ak1 = *(const bf16x8*)&Klds[cur][(16 + m) * KSTR + c * 32 + quad * 8];
                sA[0] = __builtin_amdgcn_mfma_f32_16x16x32_bf16(ak0, aq[c], sA[0], 0, 0, 0);
                sA[1] = __builtin_amdgcn_mfma_f32_16x16x32_bf16(ak1, aq[c], sA[1], 0, 0, 0);
            }
            __builtin_amdgcn_s_setprio(0);

            const int limb = q0 + w * 16 - kv0;
            float p[8], rs = 0.f;
            if (limb >= 31) {
#pragma unroll
                for (int r = 0; r < 4; ++r) {
                    p[r]     = __builtin_amdgcn_exp2f(fminf(sA[0][r], 80.f));
                    p[4 + r] = __builtin_amdgcn_exp2f(fminf(sA[1][r], 80.f));
                    rs += p[r] + p[4 + r];
                }
            } else {
                const int lim = limb + m;
#pragma unroll
                for (int r = 0; r < 4; ++r) {
                    float e0 = __builtin_amdgcn_exp2f(fminf(sA[0][r], 80.f));
                    float e1 = __builtin_amdgcn_exp2f(fminf(sA[1][r], 80.f));
                    p[r]     = (quad * 8 + r     <= lim) ? e0 : 0.f;
                    p[4 + r] = (quad * 8 + 4 + r <= lim) ? e1 : 0.f;
                    rs += p[r] + p[4 + r];
                }
            }
            lrow += rs;
#pragma unroll
            for (int r = 0; r < 4; ++r) { bp[r] = (bf16_t)p[r]; bp[4 + r] = (bf16_t)p[4 + r]; }
        }

        if (kb + 1 < nkv) {
            stage(cur ^ 1);
            if (kb + 2 < nkv) { pk += tstep; pv0 += tstep; ldregs(); }
        }

        if (active) {
            __builtin_amdgcn_s_setprio(1);
#pragma unroll
            for (int tt = 0; tt < 8; ++tt) {
                const int dd  = tt * 16 + m;
                const int grp = quad ^ ((dd >> 3) & 3);
                bf16x8 av = *(const bf16x8*)&Vt2[cur][dd * VSTR2 + grp * 4];
                o[tt] = __builtin_amdgcn_mfma_f32_16x16x32_bf16(av, bp, o[tt], 0, 0, 0);
            }
            __builtin_amdgcn_s_setprio(0);
        }
        __syncthreads();
    }

    lrow += __shfl_xor(lrow, 16);
    lrow += __shfl_xor(lrow, 32);

    {
        const float inv = 1.0f / lrow;
        float* op = out + ((size_t)qp0 * H + h) * D;
#pragma unroll
        for (int tt = 0; tt < 8; ++tt) {
            f32x4 val = o[tt] * inv;
            *(f32x4*)(op + tt * 16 + quad * 4) = val;
        }
    }
}

extern "C" void kernel_launch(void* const* d_in, const int* in_sizes, int n_in,
                              void* d_out, int out_size, void* d_ws, size_t ws_size,
                              hipStream_t stream) {
    const float* q  = (const float*)d_in[0];
    const float* kv = (const float*)d_in[1];
    float* out = (float*)d_out;
    if (d_ws != nullptr && ws_size >= WS_F32 * sizeof(float)) {
        fa_bal<<<dim3(512), dim3(512), 0, stream>>>(q, kv, out, (float*)d_ws);
        fa_merge<<<dim3(256), dim3(256), 0, stream>>>(out, (const float*)d_ws);
    } else {
        fa_fwd_r2<<<dim3(NT * H), dim3(512), 0, stream>>>(q, kv, out);
    }
}